// Round 6
// baseline (412.902 us; speedup 1.0000x reference)
//
#include <hip/hip_runtime.h>
#include <hip/hip_bf16.h>

// ResUpBlock via bf16 MFMA implicit GEMM (fp32 accumulate).
//   xT  = channels-last bf16 copy of x              [8][64][64][256]
//   t1  = lrelu(conv3x3(x,w1/48)+b1)*sqrt2 -> bf16  [8][64][64][256] (channels-last)
//   t2  = conv1x1(x, wsk/16)              -> bf16   [8][64][64][128] (channels-last)
//   u   = upsample2x(t1)                  -> bf16   [8][128][128][256] (k_synthu)
//   out = lrelu(conv3x3(u,w2/48)+b2) + up2(t2)/sqrt2  (k_conv2u, skip fused in epilogue)
// conv1/conv2u: data T14-staged in LDS (31.7 KB only); weights per-wave REGISTER
// double-buffer aq[2][4] (1-tap lookahead, L2-hot 256B-coalesced loads from the
// slab layout). __launch_bounds__(256,3) -> 3 blocks/CU (12 waves): per-tap weight
// L2 latency (~300cy) hides under the other waves' MFMAs; LDS read traffic is
// data-only (half of the round-5 weights-in-LDS version). Round-4 lesson: regs live
// across the MFMA phase must stay under the occupancy budget INCLUDING the 64-AGPR
// accumulator (VGPR_Count in rocprof excludes AGPRs) or the allocator spills to
// scratch (visible as WRITE_SIZE blowup).
// Weight slab layout [ocb][ci][tap][q][oc64][c8] (k_wt3): per-(tap,q,a) lane reads
// are 16 consecutive uint4 = 256B contiguous per quad.
// mfma_f32_16x16x32_bf16: A/B frag = 8 contiguous k per lane, C/D col=lane&15,
// row=quad*4+reg (verified per guide m89/m120).

typedef __attribute__((ext_vector_type(8))) short bf16x8;
typedef __attribute__((ext_vector_type(4))) float f32x4;

#define SQRT2F  1.41421356237309504880f
#define RSQRT2F 0.70710678118654752440f

__device__ __forceinline__ float lrelu_s(float v) { return v >= 0.f ? v : 0.2f * v; }

__device__ __forceinline__ unsigned short f2bf(float f) {
    unsigned u = __builtin_bit_cast(unsigned, f);
    u += 0x7fffu + ((u >> 16) & 1u);          // RNE
    return (unsigned short)(u >> 16);
}
__device__ __forceinline__ float bflo(unsigned u) {
    return __builtin_bit_cast(float, u << 16);
}
__device__ __forceinline__ float bfhi(unsigned u) {
    return __builtin_bit_cast(float, u & 0xffff0000u);
}

// bilinear 2x coefficients (align_corners=False, matches jax.image.resize; edge-clamped)
__device__ __forceinline__ void up2_coef(int o, int lim, int& i0, int& i1, float& w0, float& w1) {
    int h = o >> 1;
    if (o & 1) { i0 = h; i1 = (h + 1 > lim) ? lim : h + 1; w0 = 0.75f; w1 = 0.25f; }
    else       { i0 = (h - 1 < 0) ? 0 : h - 1; i1 = h;     w0 = 0.25f; w1 = 0.75f; }
}

// ---------------------------------------------------------------------------
// weight transforms
// k_wt3 output layout: [ocb][ci][tap][q][oc'][c'] (ocb=oc/64, ci=c/32, q=(c%32)/8)
// ---------------------------------------------------------------------------
__global__ __launch_bounds__(256) void k_wt3(const float* __restrict__ w,
                                             unsigned short* __restrict__ wt,
                                             int total, float scale) {
    int i = blockIdx.x * 256 + threadIdx.x;
    if (i >= total) return;
    int cp  = i & 7;
    int t1i = i >> 3;  int ocp = t1i & 63;
    int t2i = t1i >> 6; int q  = t2i & 3;
    int t3  = t2i >> 2; int tap = t3 % 9;
    int t4  = t3 / 9;   int ci  = t4 & 7; int ocb = t4 >> 3;
    int oc = (ocb << 6) + ocp;
    int c  = (ci << 5) + (q << 3) + cp;
    wt[i] = f2bf(w[(oc * 256 + c) * 9 + tap] * scale);
}

__global__ __launch_bounds__(256) void k_wt1(const float* __restrict__ w,
                                             unsigned short* __restrict__ wt,
                                             int total, float scale) {
    int i = blockIdx.x * 256 + threadIdx.x;           // [oc][c] identity layout
    if (i >= total) return;
    wt[i] = f2bf(w[i] * scale);
}

// ---------------------------------------------------------------------------
// x (NCHW f32) -> xT (channels-last bf16) via LDS transpose
// ---------------------------------------------------------------------------
__global__ __launch_bounds__(256) void k_xprep(const float* __restrict__ x,
                                               unsigned short* __restrict__ xT) {
    __shared__ float t[64][65];
    const int n = blockIdx.z, c0 = blockIdx.y << 6, p0 = blockIdx.x << 6;
    for (int i = threadIdx.x; i < 4096; i += 256) {
        int c = i >> 6, p = i & 63;
        t[c][p] = x[((size_t)(n * 256 + c0 + c) << 12) + p0 + p];
    }
    __syncthreads();
    for (int i = threadIdx.x; i < 4096; i += 256) {
        int p = i >> 6, c = i & 63;
        xT[((size_t)((n << 12) + p0 + p) << 8) + c0 + c] = f2bf(t[c][p]);
    }
}

// ---------------------------------------------------------------------------
// conv1: t1 = lrelu(conv3x3(x)+b1)*sqrt2. Data T14 in LDS; weights in regs.
// block: M=64 oc x N=256 px; grid dim3(128, 4); 3 blocks/CU target.
// ---------------------------------------------------------------------------
__global__ __launch_bounds__(256, 3) void k_conv1(
    const unsigned short* __restrict__ xT, const unsigned short* __restrict__ w1T,
    const float* __restrict__ b1, unsigned short* __restrict__ t1)
{
    __shared__ __align__(16) unsigned short dt[6][66][40];   // 31.7 KB, c padded 32->40
    const int tid = threadIdx.x;
    const int n   = blockIdx.x >> 4;
    const int y0  = (blockIdx.x & 15) << 2;
    const int ocb = blockIdx.y;
    const int oc0 = ocb << 6;
    const int w   = tid >> 6;
    const int m   = tid & 15;
    const int q   = (tid & 63) >> 4;

    f32x4 acc[4][4];
#pragma unroll
    for (int a = 0; a < 4; ++a)
#pragma unroll
        for (int g = 0; g < 4; ++g) acc[a][g] = (f32x4){0.f, 0.f, 0.f, 0.f};

    const unsigned short* wsrc = w1T + (size_t)ocb * 147456;   // 8 chunks x 18432
    const unsigned short* xTn  = xT + ((size_t)n << 20);       // n*4096*256
    unsigned short* dtf = &dt[0][0][0];
    const int loff = ((q << 6) + m) << 3;    // lane offset within a (tap,a) group

    // per-thread data staging slots: 1584 uint4 = rows 0..5 x cols 0..65 x g 0..3
    int goff[7], ldsoff[7];
#pragma unroll
    for (int k = 0; k < 7; ++k) {
        int idx = tid + (k << 8);
        goff[k] = -1; ldsoff[k] = -1;
        if (idx < 1584) {
            int r = idx / 264; int rem = idx - r * 264; int col = rem >> 2; int g = rem & 3;
            ldsoff[k] = (r * 66 + col) * 40 + (g << 3);
            int gy = y0 - 1 + r, gx = col - 1;
            if ((unsigned)gy < 64u && (unsigned)gx < 64u)
                goff[k] = (((gy << 6) + gx) << 8) + (g << 3);
        }
    }

    // prologue: issue chunk0 data loads (OOB lanes stay zero forever)
    uint4 vreg[7];
#pragma unroll
    for (int k = 0; k < 7; ++k) {
        vreg[k] = make_uint4(0, 0, 0, 0);
        if (goff[k] >= 0) vreg[k] = *(const uint4*)(xTn + goff[k]);
    }

    for (int ci = 0; ci < 8; ++ci) {
        const unsigned short* wci = wsrc + ci * 18432;
        // drain chunk ci data into LDS
#pragma unroll
        for (int k = 0; k < 7; ++k)
            if (ldsoff[k] >= 0) *(uint4*)(dtf + ldsoff[k]) = vreg[k];
        // issue chunk ci+1 data loads (fly across barrier + MFMA phase)
        if (ci < 7) {
            const int cn = (ci + 1) << 5;
#pragma unroll
            for (int k = 0; k < 7; ++k)
                if (goff[k] >= 0) vreg[k] = *(const uint4*)(xTn + goff[k] + cn);
        }
        // issue this chunk's tap-0 weight frags (latency hides under barrier)
        uint4 aq[2][4];
#pragma unroll
        for (int a = 0; a < 4; ++a)
            aq[0][a] = *(const uint4*)(wci + loff + (a << 7));
        __syncthreads();

#pragma unroll
        for (int tap = 0; tap < 9; ++tap) {
            const int cur = tap & 1;
            if (tap < 8) {
#pragma unroll
                for (int a = 0; a < 4; ++a)
                    aq[cur ^ 1][a] = *(const uint4*)(wci + loff + (a << 7) + ((tap + 1) << 11));
            }
            const int dy = tap / 3, dx = tap - 3 * (tap / 3);
            bf16x8 bfr[4];
#pragma unroll
            for (int g = 0; g < 4; ++g)
                bfr[g] = *(const bf16x8*)(&dt[w + dy][(g << 4) + m + dx][q << 3]);
#pragma unroll
            for (int a = 0; a < 4; ++a) {
                bf16x8 af = __builtin_bit_cast(bf16x8, aq[cur][a]);
#pragma unroll
                for (int g = 0; g < 4; ++g)
                    acc[a][g] = __builtin_amdgcn_mfma_f32_16x16x32_bf16(af, bfr[g], acc[a][g], 0, 0, 0);
            }
        }
        __syncthreads();
    }

    // epilogue: lane holds 4 consecutive oc (q*4+r) at px (g*16+m) -> 8B bf16 stores
    const int y = y0 + w;
#pragma unroll
    for (int a = 0; a < 4; ++a) {
        const int oc = oc0 + (a << 4) + (q << 2);
        float b0 = b1[oc], b1v = b1[oc + 1], b2v = b1[oc + 2], b3 = b1[oc + 3];
#pragma unroll
        for (int g = 0; g < 4; ++g) {
            const int xcol = (g << 4) + m;
            unsigned lo = (unsigned)f2bf(lrelu_s(acc[a][g][0] + b0) * SQRT2F)
                        | ((unsigned)f2bf(lrelu_s(acc[a][g][1] + b1v) * SQRT2F) << 16);
            unsigned hi = (unsigned)f2bf(lrelu_s(acc[a][g][2] + b2v) * SQRT2F)
                        | ((unsigned)f2bf(lrelu_s(acc[a][g][3] + b3) * SQRT2F) << 16);
            uint2 s; s.x = lo; s.y = hi;
            *(uint2*)(t1 + (((n << 12) + (y << 6) + xcol) << 8) + oc) = s;
        }
    }
}

// ---------------------------------------------------------------------------
// skip GEMM: t2[px][oc] = sum_c xT[px][c]*wsT[oc][c]
// ---------------------------------------------------------------------------
__global__ __launch_bounds__(256, 2) void k_skip(
    const unsigned short* __restrict__ xT, const unsigned short* __restrict__ wsT,
    unsigned short* __restrict__ t2)
{
    const int tid = threadIdx.x;
    const int w = tid >> 6, m = tid & 15, q = (tid & 63) >> 4;
    const int px0 = blockIdx.x << 6;
    const int apx = px0 + (w << 4) + m;

    f32x4 acc[8];
#pragma unroll
    for (int g = 0; g < 8; ++g) acc[g] = (f32x4){0.f, 0.f, 0.f, 0.f};

#pragma unroll
    for (int c0 = 0; c0 < 256; c0 += 32) {
        bf16x8 af = *(const bf16x8*)(xT + ((size_t)apx << 8) + c0 + (q << 3));
#pragma unroll
        for (int g = 0; g < 8; ++g) {
            bf16x8 bf = *(const bf16x8*)(wsT + (((g << 4) + m) << 8) + c0 + (q << 3));
            acc[g] = __builtin_amdgcn_mfma_f32_16x16x32_bf16(af, bf, acc[g], 0, 0, 0);
        }
    }
#pragma unroll
    for (int g = 0; g < 8; ++g) {
        const int oc = (g << 4) + m;
#pragma unroll
        for (int r = 0; r < 4; ++r) {
            int opx = px0 + (w << 4) + (q << 2) + r;
            t2[((size_t)opx << 7) + oc] = f2bf(acc[g][r]);
        }
    }
}

// ---------------------------------------------------------------------------
// k_synthu: u[n][oy][ox][c] = bilinear2x(t1), bf16 channels-last.
// grid dim3(2, 128, 8)
// ---------------------------------------------------------------------------
__global__ __launch_bounds__(256) void k_synthu(
    const unsigned short* __restrict__ t1, unsigned short* __restrict__ u)
{
    const int n = blockIdx.z, oy = blockIdx.y, x0 = blockIdx.x << 6;
    int ry0, ry1; float wy0, wy1;
    up2_coef(oy, 63, ry0, ry1, wy0, wy1);
    const unsigned short* tb = t1 + ((size_t)n << 20);           // n*4096*256
    unsigned short* ub = u + ((size_t)((n << 7) + oy) << 15);    // row = 128*256 elems

    for (int idx = threadIdx.x; idx < 2048; idx += 256) {
        const int ox = x0 + (idx >> 5), g = idx & 31;
        int cx0, cx1; float wx0, wx1;
        up2_coef(ox, 63, cx0, cx1, wx0, wx1);
        const int co = g << 3;
        uint4 v00 = *(const uint4*)(tb + (((ry0 << 6) + cx0) << 8) + co);
        uint4 v01 = *(const uint4*)(tb + (((ry0 << 6) + cx1) << 8) + co);
        uint4 v10 = *(const uint4*)(tb + (((ry1 << 6) + cx0) << 8) + co);
        uint4 v11 = *(const uint4*)(tb + (((ry1 << 6) + cx1) << 8) + co);
        const unsigned* pa = (const unsigned*)&v00; const unsigned* pb = (const unsigned*)&v01;
        const unsigned* pc = (const unsigned*)&v10; const unsigned* pd = (const unsigned*)&v11;
        uint4 res; unsigned* pr = (unsigned*)&res;
#pragma unroll
        for (int j = 0; j < 4; ++j) {
            float vlo = wy0 * (wx0 * bflo(pa[j]) + wx1 * bflo(pb[j]))
                      + wy1 * (wx0 * bflo(pc[j]) + wx1 * bflo(pd[j]));
            float vhi = wy0 * (wx0 * bfhi(pa[j]) + wx1 * bfhi(pb[j]))
                      + wy1 * (wx0 * bfhi(pc[j]) + wx1 * bfhi(pd[j]));
            pr[j] = (unsigned)f2bf(vlo) | ((unsigned)f2bf(vhi) << 16);
        }
        *(uint4*)(ub + (ox << 8) + co) = res;
    }
}

// ---------------------------------------------------------------------------
// k_conv2u: out = lrelu(conv3x3(u)+b2) + up2(t2)*RSQRT2. Data T14 in LDS;
// weights in regs. block: M=64 oc x N=256 px; grid dim3(512, 2); 3 blocks/CU.
// ---------------------------------------------------------------------------
__global__ __launch_bounds__(256, 3) void k_conv2u(
    const unsigned short* __restrict__ u, const unsigned short* __restrict__ w2T,
    const unsigned short* __restrict__ t2, const float* __restrict__ b2,
    float* __restrict__ out)
{
    __shared__ __align__(16) unsigned short dt[6][66][40];   // 31.7 KB
    const int tid  = threadIdx.x;
    const int n    = blockIdx.x >> 6;
    const int rest = blockIdx.x & 63;
    const int oy0  = (rest >> 1) << 2;
    const int x0   = (rest & 1) << 6;
    const int ocb  = blockIdx.y;
    const int oc0  = ocb << 6;
    const int w    = tid >> 6;
    const int m    = tid & 15;
    const int q    = (tid & 63) >> 4;

    f32x4 acc[4][4];
#pragma unroll
    for (int a = 0; a < 4; ++a)
#pragma unroll
        for (int g = 0; g < 4; ++g) acc[a][g] = (f32x4){0.f, 0.f, 0.f, 0.f};

    const unsigned short* wsrc = w2T + (size_t)ocb * 147456;
    const unsigned short* ub   = u + ((size_t)n << 22);      // n*16384*256
    unsigned short* dtf = &dt[0][0][0];
    const int loff = ((q << 6) + m) << 3;

    int goff[7], ldsoff[7];
#pragma unroll
    for (int k = 0; k < 7; ++k) {
        int idx = tid + (k << 8);
        goff[k] = -1; ldsoff[k] = -1;
        if (idx < 1584) {
            int r = idx / 264; int rem = idx - r * 264; int col = rem >> 2; int g = rem & 3;
            ldsoff[k] = (r * 66 + col) * 40 + (g << 3);
            int gy = oy0 - 1 + r, gx = x0 - 1 + col;
            if ((unsigned)gy < 128u && (unsigned)gx < 128u)
                goff[k] = (((gy << 7) + gx) << 8) + (g << 3);
        }
    }

    uint4 vreg[7];
#pragma unroll
    for (int k = 0; k < 7; ++k) {
        vreg[k] = make_uint4(0, 0, 0, 0);
        if (goff[k] >= 0) vreg[k] = *(const uint4*)(ub + goff[k]);
    }

    for (int ci = 0; ci < 8; ++ci) {
        const unsigned short* wci = wsrc + ci * 18432;
#pragma unroll
        for (int k = 0; k < 7; ++k)
            if (ldsoff[k] >= 0) *(uint4*)(dtf + ldsoff[k]) = vreg[k];
        if (ci < 7) {
            const int cn = (ci + 1) << 5;
#pragma unroll
            for (int k = 0; k < 7; ++k)
                if (goff[k] >= 0) vreg[k] = *(const uint4*)(ub + goff[k] + cn);
        }
        uint4 aq[2][4];
#pragma unroll
        for (int a = 0; a < 4; ++a)
            aq[0][a] = *(const uint4*)(wci + loff + (a << 7));
        __syncthreads();

#pragma unroll
        for (int tap = 0; tap < 9; ++tap) {
            const int cur = tap & 1;
            if (tap < 8) {
#pragma unroll
                for (int a = 0; a < 4; ++a)
                    aq[cur ^ 1][a] = *(const uint4*)(wci + loff + (a << 7) + ((tap + 1) << 11));
            }
            const int dy = tap / 3, dx = tap - 3 * (tap / 3);
            bf16x8 bfr[4];
#pragma unroll
            for (int g = 0; g < 4; ++g)
                bfr[g] = *(const bf16x8*)(&dt[w + dy][(g << 4) + m + dx][q << 3]);
#pragma unroll
            for (int a = 0; a < 4; ++a) {
                bf16x8 af = __builtin_bit_cast(bf16x8, aq[cur][a]);
#pragma unroll
                for (int g = 0; g < 4; ++g)
                    acc[a][g] = __builtin_amdgcn_mfma_f32_16x16x32_bf16(af, bfr[g], acc[a][g], 0, 0, 0);
            }
        }
        __syncthreads();
    }

    // epilogue: out[n][oc][oy][ox] = lrelu(acc+b2) + up2(t2)*RSQRT2  (pure store)
    const int oy = oy0 + w;
    int ry0, ry1; float wy0, wy1;
    up2_coef(oy, 63, ry0, ry1, wy0, wy1);
    const unsigned short* t2b = t2 + ((size_t)n << 19);      // n*4096*128
#pragma unroll
    for (int a = 0; a < 4; ++a) {
        const int oc = oc0 + (a << 4) + (q << 2);
        float bb[4] = {b2[oc], b2[oc + 1], b2[oc + 2], b2[oc + 3]};
        float* pbase = out + ((size_t)(((n << 7) + oc) << 7) + oy) * 128;
#pragma unroll
        for (int g = 0; g < 4; ++g) {
            const int ox = x0 + (g << 4) + m;
            int cx0, cx1; float wx0, wx1;
            up2_coef(ox, 63, cx0, cx1, wx0, wx1);
            uint2 A = *(const uint2*)(t2b + (((ry0 << 6) + cx0) << 7) + oc);
            uint2 B = *(const uint2*)(t2b + (((ry0 << 6) + cx1) << 7) + oc);
            uint2 C = *(const uint2*)(t2b + (((ry1 << 6) + cx0) << 7) + oc);
            uint2 D = *(const uint2*)(t2b + (((ry1 << 6) + cx1) << 7) + oc);
            const unsigned* pA = (const unsigned*)&A; const unsigned* pB = (const unsigned*)&B;
            const unsigned* pC = (const unsigned*)&C; const unsigned* pD = (const unsigned*)&D;
#pragma unroll
            for (int r = 0; r < 4; ++r) {
                unsigned wa = pA[r >> 1], wb = pB[r >> 1], wc_ = pC[r >> 1], wd = pD[r >> 1];
                float va = (r & 1) ? bfhi(wa) : bflo(wa);
                float vb = (r & 1) ? bfhi(wb) : bflo(wb);
                float vc = (r & 1) ? bfhi(wc_) : bflo(wc_);
                float vd = (r & 1) ? bfhi(wd) : bflo(wd);
                float sk = wy0 * (wx0 * va + wx1 * vb) + wy1 * (wx0 * vc + wx1 * vd);
                pbase[(size_t)r * 16384 + ox] = lrelu_s(acc[a][g][r] + bb[r]) + sk * RSQRT2F;
            }
        }
    }
}

// ---------------------------------------------------------------------------
extern "C" void kernel_launch(void* const* d_in, const int* in_sizes, int n_in,
                              void* d_out, int out_size, void* d_ws, size_t ws_size,
                              hipStream_t stream)
{
    const float* x   = (const float*)d_in[0];
    const float* w1  = (const float*)d_in[1];
    const float* b1  = (const float*)d_in[2];
    const float* w2  = (const float*)d_in[3];
    const float* b2  = (const float*)d_in[4];
    const float* wsk = (const float*)d_in[5];
    float* out = (float*)d_out;

    unsigned short* xT  = (unsigned short*)d_ws;        // 8,388,608 elems
    unsigned short* t1  = xT + 8388608;                 // 8,388,608
    unsigned short* t2  = t1 + 8388608;                 // 4,194,304
    unsigned short* w1T = t2 + 4194304;                 // 589,824
    unsigned short* w2T = w1T + 589824;                 // 294,912
    unsigned short* wsT = w2T + 294912;                 // 32,768
    unsigned short* u   = wsT + 32768;                  // 33,554,432 (~110.9 MB total)

    k_wt3   <<<dim3(2304), 256, 0, stream>>>(w1, w1T, 589824, 1.0f / 48.0f);
    k_wt3   <<<dim3(1152), 256, 0, stream>>>(w2, w2T, 294912, 1.0f / 48.0f);
    k_wt1   <<<dim3(128),  256, 0, stream>>>(wsk, wsT, 32768, 1.0f / 16.0f);
    k_xprep <<<dim3(64, 4, 8), 256, 0, stream>>>(x, xT);
    k_conv1 <<<dim3(128, 4), 256, 0, stream>>>(xT, w1T, b1, t1);
    k_skip  <<<dim3(512), 256, 0, stream>>>(xT, wsT, t2);
    k_synthu<<<dim3(2, 128, 8), 256, 0, stream>>>(t1, u);
    k_conv2u<<<dim3(512, 2), 256, 0, stream>>>(u, w2T, t2, b2, out);
}

// Round 7
// 276.290 us; speedup vs baseline: 1.4944x; 1.4944x over previous
//
#include <hip/hip_runtime.h>
#include <hip/hip_bf16.h>

// ResUpBlock via bf16 MFMA implicit GEMM (fp32 accumulate).
//   xT  = channels-last bf16 copy of x              [8][64][64][256]
//   t1  = lrelu(conv3x3(x,w1/48)+b1)*sqrt2 -> bf16  [8][64][64][256] (channels-last)
//   t2  = conv1x1(x, wsk/16)              -> bf16   [8][64][64][128] (channels-last)
//   u   = upsample2x(t1)                  -> bf16   [8][128][128][256] (k_synthu)
//   out = lrelu(conv3x3(u,w2/48)+b2) + up2(t2)/sqrt2  (k_conv2u, skip fused in epilogue)
// conv1/conv2u (round-5 proven structure): data T14-staged (vreg prefetch one chunk
// ahead, flies across barrier + MFMA phase); weights staged SAME-CHUNK into LDS via
// short-lived temp regs (L2-hot, covered by data ds_writes). MFMA phase = pure
// LDS + MFMA, zero global ops (round-6 lesson: per-tap global weight loads re-expose
// L2 latency, 107->194us). setprio(1) wraps the MFMA phase (T5: two independent
// blocks/CU give phase diversity). Round-4 lesson: no long-lived regs across the
// MFMA phase beyond vreg+acc or the allocator spills (WRITE_SIZE blowup).
// Weight slab layout [ocb][ci][tap][q][oc64][c8]: chunk slab contiguous 36.9KB.
// mfma_f32_16x16x32_bf16: A/B frag = 8 contiguous k per lane, C/D col=lane&15,
// row=quad*4+reg (verified per guide m89/m120).

typedef __attribute__((ext_vector_type(8))) short bf16x8;
typedef __attribute__((ext_vector_type(4))) float f32x4;

#define SQRT2F  1.41421356237309504880f
#define RSQRT2F 0.70710678118654752440f

__device__ __forceinline__ float lrelu_s(float v) { return v >= 0.f ? v : 0.2f * v; }

__device__ __forceinline__ unsigned short f2bf(float f) {
    unsigned u = __builtin_bit_cast(unsigned, f);
    u += 0x7fffu + ((u >> 16) & 1u);          // RNE
    return (unsigned short)(u >> 16);
}
__device__ __forceinline__ float bflo(unsigned u) {
    return __builtin_bit_cast(float, u << 16);
}
__device__ __forceinline__ float bfhi(unsigned u) {
    return __builtin_bit_cast(float, u & 0xffff0000u);
}

// bilinear 2x coefficients (align_corners=False, matches jax.image.resize; edge-clamped)
__device__ __forceinline__ void up2_coef(int o, int lim, int& i0, int& i1, float& w0, float& w1) {
    int h = o >> 1;
    if (o & 1) { i0 = h; i1 = (h + 1 > lim) ? lim : h + 1; w0 = 0.75f; w1 = 0.25f; }
    else       { i0 = (h - 1 < 0) ? 0 : h - 1; i1 = h;     w0 = 0.25f; w1 = 0.75f; }
}

// ---------------------------------------------------------------------------
// merged weight transform: w1 (3x3), w2 (3x3), wsk (1x1) in one dispatch.
// 3x3 output layout: [ocb][ci][tap][q][oc'][c']; 1x1: [oc][c] identity.
// ---------------------------------------------------------------------------
__global__ __launch_bounds__(256) void k_wtall(const float* __restrict__ w1,
                                               const float* __restrict__ w2,
                                               const float* __restrict__ wsk,
                                               unsigned short* __restrict__ w1T,
                                               unsigned short* __restrict__ w2T,
                                               unsigned short* __restrict__ wsT) {
    int i = blockIdx.x * 256 + threadIdx.x;
    if (i < 589824) {                                  // w1: 256oc x 256c x 9
        int cp  = i & 7;
        int t1i = i >> 3;  int ocp = t1i & 63;
        int t2i = t1i >> 6; int q  = t2i & 3;
        int t3  = t2i >> 2; int tap = t3 % 9;
        int t4  = t3 / 9;   int ci  = t4 & 7; int ocb = t4 >> 3;
        int oc = (ocb << 6) + ocp;
        int c  = (ci << 5) + (q << 3) + cp;
        w1T[i] = f2bf(w1[(oc * 256 + c) * 9 + tap] * (1.0f / 48.0f));
    } else if (i < 589824 + 294912) {                  // w2: 128oc x 256c x 9
        int j = i - 589824;
        int cp  = j & 7;
        int t1i = j >> 3;  int ocp = t1i & 63;
        int t2i = t1i >> 6; int q  = t2i & 3;
        int t3  = t2i >> 2; int tap = t3 % 9;
        int t4  = t3 / 9;   int ci  = t4 & 7; int ocb = t4 >> 3;
        int oc = (ocb << 6) + ocp;
        int c  = (ci << 5) + (q << 3) + cp;
        w2T[j] = f2bf(w2[(oc * 256 + c) * 9 + tap] * (1.0f / 48.0f));
    } else if (i < 589824 + 294912 + 32768) {          // wsk: 128oc x 256c
        int j = i - (589824 + 294912);
        wsT[j] = f2bf(wsk[j] * (1.0f / 16.0f));
    }
}

// ---------------------------------------------------------------------------
// x (NCHW f32) -> xT (channels-last bf16) via LDS transpose
// ---------------------------------------------------------------------------
__global__ __launch_bounds__(256) void k_xprep(const float* __restrict__ x,
                                               unsigned short* __restrict__ xT) {
    __shared__ float t[64][65];
    const int n = blockIdx.z, c0 = blockIdx.y << 6, p0 = blockIdx.x << 6;
    for (int i = threadIdx.x; i < 4096; i += 256) {
        int c = i >> 6, p = i & 63;
        t[c][p] = x[((size_t)(n * 256 + c0 + c) << 12) + p0 + p];
    }
    __syncthreads();
    for (int i = threadIdx.x; i < 4096; i += 256) {
        int p = i >> 6, c = i & 63;
        xT[((size_t)((n << 12) + p0 + p) << 8) + c0 + c] = f2bf(t[c][p]);
    }
}

// ---------------------------------------------------------------------------
// conv1: t1 = lrelu(conv3x3(x)+b1)*sqrt2. Data vreg-prefetched, weights
// drain-staged same-chunk into LDS. block: M=64 oc x N=256 px; grid dim3(128, 4)
// ---------------------------------------------------------------------------
__global__ __launch_bounds__(256, 2) void k_conv1(
    const unsigned short* __restrict__ xT, const unsigned short* __restrict__ w1T,
    const float* __restrict__ b1, unsigned short* __restrict__ t1)
{
    __shared__ __align__(16) unsigned short dt[6][66][40];   // 31.7 KB, c padded 32->40
    __shared__ __align__(16) unsigned short wl[18432];       // 36.9 KB weight slab
    const int tid = threadIdx.x;
    const int n   = blockIdx.x >> 4;
    const int y0  = (blockIdx.x & 15) << 2;
    const int ocb = blockIdx.y;
    const int oc0 = ocb << 6;
    const int w   = tid >> 6;
    const int m   = tid & 15;
    const int q   = (tid & 63) >> 4;

    f32x4 acc[4][4];
#pragma unroll
    for (int a = 0; a < 4; ++a)
#pragma unroll
        for (int g = 0; g < 4; ++g) acc[a][g] = (f32x4){0.f, 0.f, 0.f, 0.f};

    const unsigned short* wsrc = w1T + (size_t)ocb * 147456;   // 8 chunks x 18432
    const unsigned short* xTn  = xT + ((size_t)n << 20);       // n*4096*256
    unsigned short* dtf = &dt[0][0][0];

    // per-thread data staging slots: 1584 uint4 = rows 0..5 x cols 0..65 x g 0..3
    int goff[7], ldsoff[7];
#pragma unroll
    for (int k = 0; k < 7; ++k) {
        int idx = tid + (k << 8);
        goff[k] = -1; ldsoff[k] = -1;
        if (idx < 1584) {
            int r = idx / 264; int rem = idx - r * 264; int col = rem >> 2; int g = rem & 3;
            ldsoff[k] = (r * 66 + col) * 40 + (g << 3);
            int gy = y0 - 1 + r, gx = col - 1;
            if ((unsigned)gy < 64u && (unsigned)gx < 64u)
                goff[k] = (((gy << 6) + gx) << 8) + (g << 3);
        }
    }

    // prologue: issue chunk0 data loads (OOB lanes stay zero forever)
    uint4 vreg[7];
#pragma unroll
    for (int k = 0; k < 7; ++k) {
        vreg[k] = make_uint4(0, 0, 0, 0);
        if (goff[k] >= 0) vreg[k] = *(const uint4*)(xTn + goff[k]);
    }

    for (int ci = 0; ci < 8; ++ci) {
        // (a) issue THIS chunk's weight slab loads (L2-hot, short-lived regs)
        uint4 twreg[9];
        const unsigned short* wc = wsrc + ci * 18432;
#pragma unroll
        for (int j = 0; j < 9; ++j)
            twreg[j] = *(const uint4*)(wc + ((tid + (j << 8)) << 3));
        // (b) drain chunk ci data into LDS (covers part of the weight L2 latency)
#pragma unroll
        for (int k = 0; k < 7; ++k)
            if (ldsoff[k] >= 0) *(uint4*)(dtf + ldsoff[k]) = vreg[k];
        // (c) issue chunk ci+1 data loads: in flight across barrier + MFMA phase
        if (ci < 7) {
            const int cn = (ci + 1) << 5;
#pragma unroll
            for (int k = 0; k < 7; ++k)
                if (goff[k] >= 0) vreg[k] = *(const uint4*)(xTn + goff[k] + cn);
        }
        // (d) weights -> LDS (twreg dies here; not live across MFMA phase)
#pragma unroll
        for (int j = 0; j < 9; ++j)
            *(uint4*)(wl + ((tid + (j << 8)) << 3)) = twreg[j];
        __syncthreads();

        // pure LDS + MFMA phase (no global ops); T5 priority boost
        __builtin_amdgcn_s_setprio(1);
#pragma unroll
        for (int tap = 0; tap < 9; ++tap) {
            const int dy = tap / 3, dx = tap - 3 * (tap / 3);
            bf16x8 bfr[4];
#pragma unroll
            for (int g = 0; g < 4; ++g)
                bfr[g] = *(const bf16x8*)(&dt[w + dy][(g << 4) + m + dx][q << 3]);
#pragma unroll
            for (int a = 0; a < 4; ++a) {
                bf16x8 af = *(const bf16x8*)(wl + (((((tap << 2) + q) << 6) + (a << 4) + m) << 3));
#pragma unroll
                for (int g = 0; g < 4; ++g)
                    acc[a][g] = __builtin_amdgcn_mfma_f32_16x16x32_bf16(af, bfr[g], acc[a][g], 0, 0, 0);
            }
        }
        __builtin_amdgcn_s_setprio(0);
        __syncthreads();
    }

    // epilogue: lane holds 4 consecutive oc (q*4+r) at px (g*16+m) -> 8B bf16 stores
    const int y = y0 + w;
#pragma unroll
    for (int a = 0; a < 4; ++a) {
        const int oc = oc0 + (a << 4) + (q << 2);
        float b0 = b1[oc], b1v = b1[oc + 1], b2v = b1[oc + 2], b3 = b1[oc + 3];
#pragma unroll
        for (int g = 0; g < 4; ++g) {
            const int xcol = (g << 4) + m;
            unsigned lo = (unsigned)f2bf(lrelu_s(acc[a][g][0] + b0) * SQRT2F)
                        | ((unsigned)f2bf(lrelu_s(acc[a][g][1] + b1v) * SQRT2F) << 16);
            unsigned hi = (unsigned)f2bf(lrelu_s(acc[a][g][2] + b2v) * SQRT2F)
                        | ((unsigned)f2bf(lrelu_s(acc[a][g][3] + b3) * SQRT2F) << 16);
            uint2 s; s.x = lo; s.y = hi;
            *(uint2*)(t1 + (((n << 12) + (y << 6) + xcol) << 8) + oc) = s;
        }
    }
}

// ---------------------------------------------------------------------------
// skip GEMM: t2[px][oc] = sum_c xT[px][c]*wsT[oc][c]
// ---------------------------------------------------------------------------
__global__ __launch_bounds__(256, 2) void k_skip(
    const unsigned short* __restrict__ xT, const unsigned short* __restrict__ wsT,
    unsigned short* __restrict__ t2)
{
    const int tid = threadIdx.x;
    const int w = tid >> 6, m = tid & 15, q = (tid & 63) >> 4;
    const int px0 = blockIdx.x << 6;
    const int apx = px0 + (w << 4) + m;

    f32x4 acc[8];
#pragma unroll
    for (int g = 0; g < 8; ++g) acc[g] = (f32x4){0.f, 0.f, 0.f, 0.f};

#pragma unroll
    for (int c0 = 0; c0 < 256; c0 += 32) {
        bf16x8 af = *(const bf16x8*)(xT + ((size_t)apx << 8) + c0 + (q << 3));
#pragma unroll
        for (int g = 0; g < 8; ++g) {
            bf16x8 bf = *(const bf16x8*)(wsT + (((g << 4) + m) << 8) + c0 + (q << 3));
            acc[g] = __builtin_amdgcn_mfma_f32_16x16x32_bf16(af, bf, acc[g], 0, 0, 0);
        }
    }
#pragma unroll
    for (int g = 0; g < 8; ++g) {
        const int oc = (g << 4) + m;
#pragma unroll
        for (int r = 0; r < 4; ++r) {
            int opx = px0 + (w << 4) + (q << 2) + r;
            t2[((size_t)opx << 7) + oc] = f2bf(acc[g][r]);
        }
    }
}

// ---------------------------------------------------------------------------
// k_synthu: u[n][oy][ox][c] = bilinear2x(t1), bf16 channels-last.
// grid dim3(2, 128, 8)
// ---------------------------------------------------------------------------
__global__ __launch_bounds__(256) void k_synthu(
    const unsigned short* __restrict__ t1, unsigned short* __restrict__ u)
{
    const int n = blockIdx.z, oy = blockIdx.y, x0 = blockIdx.x << 6;
    int ry0, ry1; float wy0, wy1;
    up2_coef(oy, 63, ry0, ry1, wy0, wy1);
    const unsigned short* tb = t1 + ((size_t)n << 20);           // n*4096*256
    unsigned short* ub = u + ((size_t)((n << 7) + oy) << 15);    // row = 128*256 elems

    for (int idx = threadIdx.x; idx < 2048; idx += 256) {
        const int ox = x0 + (idx >> 5), g = idx & 31;
        int cx0, cx1; float wx0, wx1;
        up2_coef(ox, 63, cx0, cx1, wx0, wx1);
        const int co = g << 3;
        uint4 v00 = *(const uint4*)(tb + (((ry0 << 6) + cx0) << 8) + co);
        uint4 v01 = *(const uint4*)(tb + (((ry0 << 6) + cx1) << 8) + co);
        uint4 v10 = *(const uint4*)(tb + (((ry1 << 6) + cx0) << 8) + co);
        uint4 v11 = *(const uint4*)(tb + (((ry1 << 6) + cx1) << 8) + co);
        const unsigned* pa = (const unsigned*)&v00; const unsigned* pb = (const unsigned*)&v01;
        const unsigned* pc = (const unsigned*)&v10; const unsigned* pd = (const unsigned*)&v11;
        uint4 res; unsigned* pr = (unsigned*)&res;
#pragma unroll
        for (int j = 0; j < 4; ++j) {
            float vlo = wy0 * (wx0 * bflo(pa[j]) + wx1 * bflo(pb[j]))
                      + wy1 * (wx0 * bflo(pc[j]) + wx1 * bflo(pd[j]));
            float vhi = wy0 * (wx0 * bfhi(pa[j]) + wx1 * bfhi(pb[j]))
                      + wy1 * (wx0 * bfhi(pc[j]) + wx1 * bfhi(pd[j]));
            pr[j] = (unsigned)f2bf(vlo) | ((unsigned)f2bf(vhi) << 16);
        }
        *(uint4*)(ub + (ox << 8) + co) = res;
    }
}

// ---------------------------------------------------------------------------
// k_conv2u: out = lrelu(conv3x3(u)+b2) + up2(t2)*RSQRT2. Data vreg-prefetched,
// weights drain-staged same-chunk into LDS. block: M=64 oc x N=256 px;
// grid dim3(512, 2)
// ---------------------------------------------------------------------------
__global__ __launch_bounds__(256, 2) void k_conv2u(
    const unsigned short* __restrict__ u, const unsigned short* __restrict__ w2T,
    const unsigned short* __restrict__ t2, const float* __restrict__ b2,
    float* __restrict__ out)
{
    __shared__ __align__(16) unsigned short dt[6][66][40];   // 31.7 KB
    __shared__ __align__(16) unsigned short wl[18432];       // 36.9 KB
    const int tid  = threadIdx.x;
    const int n    = blockIdx.x >> 6;
    const int rest = blockIdx.x & 63;
    const int oy0  = (rest >> 1) << 2;
    const int x0   = (rest & 1) << 6;
    const int ocb  = blockIdx.y;
    const int oc0  = ocb << 6;
    const int w    = tid >> 6;
    const int m    = tid & 15;
    const int q    = (tid & 63) >> 4;

    f32x4 acc[4][4];
#pragma unroll
    for (int a = 0; a < 4; ++a)
#pragma unroll
        for (int g = 0; g < 4; ++g) acc[a][g] = (f32x4){0.f, 0.f, 0.f, 0.f};

    const unsigned short* wsrc = w2T + (size_t)ocb * 147456;
    const unsigned short* ub   = u + ((size_t)n << 22);      // n*16384*256
    unsigned short* dtf = &dt[0][0][0];

    int goff[7], ldsoff[7];
#pragma unroll
    for (int k = 0; k < 7; ++k) {
        int idx = tid + (k << 8);
        goff[k] = -1; ldsoff[k] = -1;
        if (idx < 1584) {
            int r = idx / 264; int rem = idx - r * 264; int col = rem >> 2; int g = rem & 3;
            ldsoff[k] = (r * 66 + col) * 40 + (g << 3);
            int gy = oy0 - 1 + r, gx = x0 - 1 + col;
            if ((unsigned)gy < 128u && (unsigned)gx < 128u)
                goff[k] = (((gy << 7) + gx) << 8) + (g << 3);
        }
    }

    uint4 vreg[7];
#pragma unroll
    for (int k = 0; k < 7; ++k) {
        vreg[k] = make_uint4(0, 0, 0, 0);
        if (goff[k] >= 0) vreg[k] = *(const uint4*)(ub + goff[k]);
    }

    for (int ci = 0; ci < 8; ++ci) {
        // (a) issue THIS chunk's weight slab loads (L2-hot, short-lived regs)
        uint4 twreg[9];
        const unsigned short* wc = wsrc + ci * 18432;
#pragma unroll
        for (int j = 0; j < 9; ++j)
            twreg[j] = *(const uint4*)(wc + ((tid + (j << 8)) << 3));
        // (b) drain chunk ci data into LDS
#pragma unroll
        for (int k = 0; k < 7; ++k)
            if (ldsoff[k] >= 0) *(uint4*)(dtf + ldsoff[k]) = vreg[k];
        // (c) issue chunk ci+1 data loads
        if (ci < 7) {
            const int cn = (ci + 1) << 5;
#pragma unroll
            for (int k = 0; k < 7; ++k)
                if (goff[k] >= 0) vreg[k] = *(const uint4*)(ub + goff[k] + cn);
        }
        // (d) weights -> LDS (twreg dies here)
#pragma unroll
        for (int j = 0; j < 9; ++j)
            *(uint4*)(wl + ((tid + (j << 8)) << 3)) = twreg[j];
        __syncthreads();

        __builtin_amdgcn_s_setprio(1);
#pragma unroll
        for (int tap = 0; tap < 9; ++tap) {
            const int dy = tap / 3, dx = tap - 3 * (tap / 3);
            bf16x8 bfr[4];
#pragma unroll
            for (int g = 0; g < 4; ++g)
                bfr[g] = *(const bf16x8*)(&dt[w + dy][(g << 4) + m + dx][q << 3]);
#pragma unroll
            for (int a = 0; a < 4; ++a) {
                bf16x8 af = *(const bf16x8*)(wl + (((((tap << 2) + q) << 6) + (a << 4) + m) << 3));
#pragma unroll
                for (int g = 0; g < 4; ++g)
                    acc[a][g] = __builtin_amdgcn_mfma_f32_16x16x32_bf16(af, bfr[g], acc[a][g], 0, 0, 0);
            }
        }
        __builtin_amdgcn_s_setprio(0);
        __syncthreads();
    }

    // epilogue: out[n][oc][oy][ox] = lrelu(acc+b2) + up2(t2)*RSQRT2  (pure store)
    const int oy = oy0 + w;
    int ry0, ry1; float wy0, wy1;
    up2_coef(oy, 63, ry0, ry1, wy0, wy1);
    const unsigned short* t2b = t2 + ((size_t)n << 19);      // n*4096*128
#pragma unroll
    for (int a = 0; a < 4; ++a) {
        const int oc = oc0 + (a << 4) + (q << 2);
        float bb[4] = {b2[oc], b2[oc + 1], b2[oc + 2], b2[oc + 3]};
        float* pbase = out + ((size_t)(((n << 7) + oc) << 7) + oy) * 128;
#pragma unroll
        for (int g = 0; g < 4; ++g) {
            const int ox = x0 + (g << 4) + m;
            int cx0, cx1; float wx0, wx1;
            up2_coef(ox, 63, cx0, cx1, wx0, wx1);
            uint2 A = *(const uint2*)(t2b + (((ry0 << 6) + cx0) << 7) + oc);
            uint2 B = *(const uint2*)(t2b + (((ry0 << 6) + cx1) << 7) + oc);
            uint2 C = *(const uint2*)(t2b + (((ry1 << 6) + cx0) << 7) + oc);
            uint2 D = *(const uint2*)(t2b + (((ry1 << 6) + cx1) << 7) + oc);
            const unsigned* pA = (const unsigned*)&A; const unsigned* pB = (const unsigned*)&B;
            const unsigned* pC = (const unsigned*)&C; const unsigned* pD = (const unsigned*)&D;
#pragma unroll
            for (int r = 0; r < 4; ++r) {
                unsigned wa = pA[r >> 1], wb = pB[r >> 1], wc_ = pC[r >> 1], wd = pD[r >> 1];
                float va = (r & 1) ? bfhi(wa) : bflo(wa);
                float vb = (r & 1) ? bfhi(wb) : bflo(wb);
                float vc = (r & 1) ? bfhi(wc_) : bflo(wc_);
                float vd = (r & 1) ? bfhi(wd) : bflo(wd);
                float sk = wy0 * (wx0 * va + wx1 * vb) + wy1 * (wx0 * vc + wx1 * vd);
                pbase[(size_t)r * 16384 + ox] = lrelu_s(acc[a][g][r] + bb[r]) + sk * RSQRT2F;
            }
        }
    }
}

// ---------------------------------------------------------------------------
extern "C" void kernel_launch(void* const* d_in, const int* in_sizes, int n_in,
                              void* d_out, int out_size, void* d_ws, size_t ws_size,
                              hipStream_t stream)
{
    const float* x   = (const float*)d_in[0];
    const float* w1  = (const float*)d_in[1];
    const float* b1  = (const float*)d_in[2];
    const float* w2  = (const float*)d_in[3];
    const float* b2  = (const float*)d_in[4];
    const float* wsk = (const float*)d_in[5];
    float* out = (float*)d_out;

    unsigned short* xT  = (unsigned short*)d_ws;        // 8,388,608 elems
    unsigned short* t1  = xT + 8388608;                 // 8,388,608
    unsigned short* t2  = t1 + 8388608;                 // 4,194,304
    unsigned short* w1T = t2 + 4194304;                 // 589,824
    unsigned short* w2T = w1T + 589824;                 // 294,912
    unsigned short* wsT = w2T + 294912;                 // 32,768
    unsigned short* u   = wsT + 32768;                  // 33,554,432 (~110.9 MB total)

    k_wtall <<<dim3(3584), 256, 0, stream>>>(w1, w2, wsk, w1T, w2T, wsT);
    k_xprep <<<dim3(64, 4, 8), 256, 0, stream>>>(x, xT);
    k_conv1 <<<dim3(128, 4), 256, 0, stream>>>(xT, w1T, b1, t1);
    k_skip  <<<dim3(512), 256, 0, stream>>>(xT, wsT, t2);
    k_synthu<<<dim3(2, 128, 8), 256, 0, stream>>>(t1, u);
    k_conv2u<<<dim3(512, 2), 256, 0, stream>>>(u, w2T, t2, b2, out);
}

// Round 8
// 267.602 us; speedup vs baseline: 1.5430x; 1.0325x over previous
//
#include <hip/hip_runtime.h>
#include <hip/hip_bf16.h>

// ResUpBlock via bf16 MFMA implicit GEMM (fp32 accumulate).
//   xT  = channels-last bf16 copy of x              [8][64][64][256]
//   t1  = lrelu(conv3x3(x,w1/48)+b1)*sqrt2 -> bf16  [8][64][64][256] (channels-last)
//   t2  = conv1x1(x, wsk/16)              -> bf16   [8][64][64][128] (channels-last)
//   u   = upsample2x(t1)                  -> bf16   [8][128][128][256]
//   out = lrelu(conv3x3(u,w2/48)+b2) + up2(t2)/sqrt2  (k_conv2u, skip fused in epilogue)
// conv1/conv2u (round-5 proven structure): data T14-staged (vreg prefetch one chunk
// ahead); weights staged SAME-CHUNK into LDS via short-lived temp regs. MFMA phase =
// pure LDS + MFMA, zero global ops. Round-7 change: data tile re-laid out as
// channel-quad planes dt[4][6][66][8] -> each 16-lane phase reads a contiguous 256B
// run (conflict-free b128); old [6][66][40] layout had 80B col stride => lanes m,m+8
// on same bank group (constant 6.34M SQ_LDS_BANK_CONFLICT across rounds 2-7).
// Staging thread->(r,col,cg) map unchanged (keeps 64B-contiguous global coalescing).
// Round-4 lesson: no long-lived regs across MFMA phase beyond vreg+acc (spill ->
// WRITE_SIZE blowup). Round-6 lesson: per-tap global weight loads re-expose L2
// latency (107->194us).
// Weight slab layout [ocb][ci][tap][q][oc64][c8]: chunk slab contiguous 36.9KB.
// mfma_f32_16x16x32_bf16: A/B frag = 8 contiguous k per lane, C/D col=lane&15,
// row=quad*4+reg (verified per guide m89/m120).

typedef __attribute__((ext_vector_type(8))) short bf16x8;
typedef __attribute__((ext_vector_type(4))) float f32x4;

#define SQRT2F  1.41421356237309504880f
#define RSQRT2F 0.70710678118654752440f

__device__ __forceinline__ float lrelu_s(float v) { return v >= 0.f ? v : 0.2f * v; }

__device__ __forceinline__ unsigned short f2bf(float f) {
    unsigned u = __builtin_bit_cast(unsigned, f);
    u += 0x7fffu + ((u >> 16) & 1u);          // RNE
    return (unsigned short)(u >> 16);
}
__device__ __forceinline__ float bflo(unsigned u) {
    return __builtin_bit_cast(float, u << 16);
}
__device__ __forceinline__ float bfhi(unsigned u) {
    return __builtin_bit_cast(float, u & 0xffff0000u);
}

// bilinear 2x coefficients (align_corners=False, matches jax.image.resize; edge-clamped)
__device__ __forceinline__ void up2_coef(int o, int lim, int& i0, int& i1, float& w0, float& w1) {
    int h = o >> 1;
    if (o & 1) { i0 = h; i1 = (h + 1 > lim) ? lim : h + 1; w0 = 0.75f; w1 = 0.25f; }
    else       { i0 = (h - 1 < 0) ? 0 : h - 1; i1 = h;     w0 = 0.25f; w1 = 0.75f; }
}

// ---------------------------------------------------------------------------
// k_prep: merged weight transform (w1/w2 3x3 slab layout, wsk 1x1) + xT transpose.
// blocks [0,3584): weights; [3584,5632): xprep (64 px-tiles x 4 c-tiles x 8 n).
// ---------------------------------------------------------------------------
__global__ __launch_bounds__(256) void k_prep(const float* __restrict__ w1,
                                              const float* __restrict__ w2,
                                              const float* __restrict__ wsk,
                                              const float* __restrict__ x,
                                              unsigned short* __restrict__ w1T,
                                              unsigned short* __restrict__ w2T,
                                              unsigned short* __restrict__ wsT,
                                              unsigned short* __restrict__ xT) {
    __shared__ float t[64][65];
    const int b = blockIdx.x;
    if (b < 3584) {
        int i = b * 256 + threadIdx.x;
        if (i < 589824) {                                  // w1: 256oc x 256c x 9
            int cp  = i & 7;
            int t1i = i >> 3;  int ocp = t1i & 63;
            int t2i = t1i >> 6; int q  = t2i & 3;
            int t3  = t2i >> 2; int tap = t3 % 9;
            int t4  = t3 / 9;   int ci  = t4 & 7; int ocb = t4 >> 3;
            int oc = (ocb << 6) + ocp;
            int c  = (ci << 5) + (q << 3) + cp;
            w1T[i] = f2bf(w1[(oc * 256 + c) * 9 + tap] * (1.0f / 48.0f));
        } else if (i < 589824 + 294912) {                  // w2: 128oc x 256c x 9
            int j = i - 589824;
            int cp  = j & 7;
            int t1i = j >> 3;  int ocp = t1i & 63;
            int t2i = t1i >> 6; int q  = t2i & 3;
            int t3  = t2i >> 2; int tap = t3 % 9;
            int t4  = t3 / 9;   int ci  = t4 & 7; int ocb = t4 >> 3;
            int oc = (ocb << 6) + ocp;
            int c  = (ci << 5) + (q << 3) + cp;
            w2T[j] = f2bf(w2[(oc * 256 + c) * 9 + tap] * (1.0f / 48.0f));
        } else if (i < 589824 + 294912 + 32768) {          // wsk: 128oc x 256c
            int j = i - (589824 + 294912);
            wsT[j] = f2bf(wsk[j] * (1.0f / 16.0f));
        }
        return;
    }
    const int bb = b - 3584;
    const int p0 = (bb & 63) << 6, c0 = ((bb >> 6) & 3) << 6, n = bb >> 8;
    for (int i = threadIdx.x; i < 4096; i += 256) {
        int c = i >> 6, p = i & 63;
        t[c][p] = x[((size_t)(n * 256 + c0 + c) << 12) + p0 + p];
    }
    __syncthreads();
    for (int i = threadIdx.x; i < 4096; i += 256) {
        int p = i >> 6, c = i & 63;
        xT[((size_t)((n << 12) + p0 + p) << 8) + c0 + c] = f2bf(t[c][p]);
    }
}

// ---------------------------------------------------------------------------
// conv1: t1 = lrelu(conv3x3(x)+b1)*sqrt2. Data vreg-prefetched, weights
// drain-staged same-chunk into LDS. block: M=64 oc x N=256 px; grid dim3(128, 4)
// ---------------------------------------------------------------------------
__global__ __launch_bounds__(256, 2) void k_conv1(
    const unsigned short* __restrict__ xT, const unsigned short* __restrict__ w1T,
    const float* __restrict__ b1, unsigned short* __restrict__ t1)
{
    __shared__ __align__(16) unsigned short dt[4][6][66][8]; // 25.3 KB, cg-planes
    __shared__ __align__(16) unsigned short wl[18432];       // 36.9 KB weight slab
    const int tid = threadIdx.x;
    const int n   = blockIdx.x >> 4;
    const int y0  = (blockIdx.x & 15) << 2;
    const int ocb = blockIdx.y;
    const int oc0 = ocb << 6;
    const int w   = tid >> 6;
    const int m   = tid & 15;
    const int q   = (tid & 63) >> 4;

    f32x4 acc[4][4];
#pragma unroll
    for (int a = 0; a < 4; ++a)
#pragma unroll
        for (int g = 0; g < 4; ++g) acc[a][g] = (f32x4){0.f, 0.f, 0.f, 0.f};

    const unsigned short* wsrc = w1T + (size_t)ocb * 147456;   // 8 chunks x 18432
    const unsigned short* xTn  = xT + ((size_t)n << 20);       // n*4096*256
    unsigned short* dtf = &dt[0][0][0][0];

    // staging slots: 1584 uint4; idx -> (r, col, cg) mapping UNCHANGED (coalescing);
    // LDS offset uses cg-plane layout: ((cg*396) + r*66 + col) uint4s.
    int goff[7], ldsoff[7];
#pragma unroll
    for (int k = 0; k < 7; ++k) {
        int idx = tid + (k << 8);
        goff[k] = -1; ldsoff[k] = -1;
        if (idx < 1584) {
            int r = idx / 264; int rem = idx - r * 264; int col = rem >> 2; int cg = rem & 3;
            ldsoff[k] = (cg * 396 + r * 66 + col) << 3;
            int gy = y0 - 1 + r, gx = col - 1;
            if ((unsigned)gy < 64u && (unsigned)gx < 64u)
                goff[k] = (((gy << 6) + gx) << 8) + (cg << 3);
        }
    }

    // prologue: issue chunk0 data loads (OOB lanes stay zero forever)
    uint4 vreg[7];
#pragma unroll
    for (int k = 0; k < 7; ++k) {
        vreg[k] = make_uint4(0, 0, 0, 0);
        if (goff[k] >= 0) vreg[k] = *(const uint4*)(xTn + goff[k]);
    }

    for (int ci = 0; ci < 8; ++ci) {
        // (a) issue THIS chunk's weight slab loads (L2-hot, short-lived regs)
        uint4 twreg[9];
        const unsigned short* wc = wsrc + ci * 18432;
#pragma unroll
        for (int j = 0; j < 9; ++j)
            twreg[j] = *(const uint4*)(wc + ((tid + (j << 8)) << 3));
        // (b) drain chunk ci data into LDS
#pragma unroll
        for (int k = 0; k < 7; ++k)
            if (ldsoff[k] >= 0) *(uint4*)(dtf + ldsoff[k]) = vreg[k];
        // (c) issue chunk ci+1 data loads: in flight across barrier + MFMA phase
        if (ci < 7) {
            const int cn = (ci + 1) << 5;
#pragma unroll
            for (int k = 0; k < 7; ++k)
                if (goff[k] >= 0) vreg[k] = *(const uint4*)(xTn + goff[k] + cn);
        }
        // (d) weights -> LDS (twreg dies here; not live across MFMA phase)
#pragma unroll
        for (int j = 0; j < 9; ++j)
            *(uint4*)(wl + ((tid + (j << 8)) << 3)) = twreg[j];
        __syncthreads();

        // pure LDS + MFMA phase (no global ops); T5 priority boost
        __builtin_amdgcn_s_setprio(1);
#pragma unroll
        for (int tap = 0; tap < 9; ++tap) {
            const int dy = tap / 3, dx = tap - 3 * (tap / 3);
            bf16x8 bfr[4];
#pragma unroll
            for (int g = 0; g < 4; ++g)
                bfr[g] = *(const bf16x8*)(dtf + ((q * 396 + (w + dy) * 66 + (g << 4) + m + dx) << 3));
#pragma unroll
            for (int a = 0; a < 4; ++a) {
                bf16x8 af = *(const bf16x8*)(wl + (((((tap << 2) + q) << 6) + (a << 4) + m) << 3));
#pragma unroll
                for (int g = 0; g < 4; ++g)
                    acc[a][g] = __builtin_amdgcn_mfma_f32_16x16x32_bf16(af, bfr[g], acc[a][g], 0, 0, 0);
            }
        }
        __builtin_amdgcn_s_setprio(0);
        __syncthreads();
    }

    // epilogue: lane holds 4 consecutive oc (q*4+r) at px (g*16+m) -> 8B bf16 stores
    const int y = y0 + w;
#pragma unroll
    for (int a = 0; a < 4; ++a) {
        const int oc = oc0 + (a << 4) + (q << 2);
        float b0 = b1[oc], b1v = b1[oc + 1], b2v = b1[oc + 2], b3 = b1[oc + 3];
#pragma unroll
        for (int g = 0; g < 4; ++g) {
            const int xcol = (g << 4) + m;
            unsigned lo = (unsigned)f2bf(lrelu_s(acc[a][g][0] + b0) * SQRT2F)
                        | ((unsigned)f2bf(lrelu_s(acc[a][g][1] + b1v) * SQRT2F) << 16);
            unsigned hi = (unsigned)f2bf(lrelu_s(acc[a][g][2] + b2v) * SQRT2F)
                        | ((unsigned)f2bf(lrelu_s(acc[a][g][3] + b3) * SQRT2F) << 16);
            uint2 s; s.x = lo; s.y = hi;
            *(uint2*)(t1 + (((n << 12) + (y << 6) + xcol) << 8) + oc) = s;
        }
    }
}

// ---------------------------------------------------------------------------
// k_ss: merged skip GEMM + synthu.
// blocks [0,512): skip (64 px x 128 oc GEMM); [512,2560): synthu bilinear.
// ---------------------------------------------------------------------------
__global__ __launch_bounds__(256, 2) void k_ss(
    const unsigned short* __restrict__ xT, const unsigned short* __restrict__ wsT,
    const unsigned short* __restrict__ t1, unsigned short* __restrict__ t2,
    unsigned short* __restrict__ u)
{
    const int b = blockIdx.x;
    const int tid = threadIdx.x;
    if (b < 512) {
        const int w = tid >> 6, m = tid & 15, q = (tid & 63) >> 4;
        const int px0 = b << 6;
        const int apx = px0 + (w << 4) + m;

        f32x4 acc[8];
#pragma unroll
        for (int g = 0; g < 8; ++g) acc[g] = (f32x4){0.f, 0.f, 0.f, 0.f};

#pragma unroll
        for (int c0 = 0; c0 < 256; c0 += 32) {
            bf16x8 af = *(const bf16x8*)(xT + ((size_t)apx << 8) + c0 + (q << 3));
#pragma unroll
            for (int g = 0; g < 8; ++g) {
                bf16x8 bf = *(const bf16x8*)(wsT + (((g << 4) + m) << 8) + c0 + (q << 3));
                acc[g] = __builtin_amdgcn_mfma_f32_16x16x32_bf16(af, bf, acc[g], 0, 0, 0);
            }
        }
#pragma unroll
        for (int g = 0; g < 8; ++g) {
            const int oc = (g << 4) + m;
#pragma unroll
            for (int r = 0; r < 4; ++r) {
                int opx = px0 + (w << 4) + (q << 2) + r;
                t2[((size_t)opx << 7) + oc] = f2bf(acc[g][r]);
            }
        }
        return;
    }
    // synthu: u[n][oy][ox][c] = bilinear2x(t1)
    const int bb = b - 512;
    const int n = bb >> 8, oy = (bb >> 1) & 127, x0 = (bb & 1) << 6;
    int ry0, ry1; float wy0, wy1;
    up2_coef(oy, 63, ry0, ry1, wy0, wy1);
    const unsigned short* tb = t1 + ((size_t)n << 20);           // n*4096*256
    unsigned short* ub = u + ((size_t)((n << 7) + oy) << 15);    // row = 128*256 elems

    for (int idx = tid; idx < 2048; idx += 256) {
        const int ox = x0 + (idx >> 5), g = idx & 31;
        int cx0, cx1; float wx0, wx1;
        up2_coef(ox, 63, cx0, cx1, wx0, wx1);
        const int co = g << 3;
        uint4 v00 = *(const uint4*)(tb + (((ry0 << 6) + cx0) << 8) + co);
        uint4 v01 = *(const uint4*)(tb + (((ry0 << 6) + cx1) << 8) + co);
        uint4 v10 = *(const uint4*)(tb + (((ry1 << 6) + cx0) << 8) + co);
        uint4 v11 = *(const uint4*)(tb + (((ry1 << 6) + cx1) << 8) + co);
        const unsigned* pa = (const unsigned*)&v00; const unsigned* pb = (const unsigned*)&v01;
        const unsigned* pc = (const unsigned*)&v10; const unsigned* pd = (const unsigned*)&v11;
        uint4 res; unsigned* pr = (unsigned*)&res;
#pragma unroll
        for (int j = 0; j < 4; ++j) {
            float vlo = wy0 * (wx0 * bflo(pa[j]) + wx1 * bflo(pb[j]))
                      + wy1 * (wx0 * bflo(pc[j]) + wx1 * bflo(pd[j]));
            float vhi = wy0 * (wx0 * bfhi(pa[j]) + wx1 * bfhi(pb[j]))
                      + wy1 * (wx0 * bfhi(pc[j]) + wx1 * bfhi(pd[j]));
            pr[j] = (unsigned)f2bf(vlo) | ((unsigned)f2bf(vhi) << 16);
        }
        *(uint4*)(ub + (ox << 8) + co) = res;
    }
}

// ---------------------------------------------------------------------------
// k_conv2u: out = lrelu(conv3x3(u)+b2) + up2(t2)*RSQRT2. Data vreg-prefetched,
// weights drain-staged same-chunk into LDS. block: M=64 oc x N=256 px;
// grid dim3(512, 2)
// ---------------------------------------------------------------------------
__global__ __launch_bounds__(256, 2) void k_conv2u(
    const unsigned short* __restrict__ u, const unsigned short* __restrict__ w2T,
    const unsigned short* __restrict__ t2, const float* __restrict__ b2,
    float* __restrict__ out)
{
    __shared__ __align__(16) unsigned short dt[4][6][66][8]; // 25.3 KB, cg-planes
    __shared__ __align__(16) unsigned short wl[18432];       // 36.9 KB
    const int tid  = threadIdx.x;
    const int n    = blockIdx.x >> 6;
    const int rest = blockIdx.x & 63;
    const int oy0  = (rest >> 1) << 2;
    const int x0   = (rest & 1) << 6;
    const int ocb  = blockIdx.y;
    const int oc0  = ocb << 6;
    const int w    = tid >> 6;
    const int m    = tid & 15;
    const int q    = (tid & 63) >> 4;

    f32x4 acc[4][4];
#pragma unroll
    for (int a = 0; a < 4; ++a)
#pragma unroll
        for (int g = 0; g < 4; ++g) acc[a][g] = (f32x4){0.f, 0.f, 0.f, 0.f};

    const unsigned short* wsrc = w2T + (size_t)ocb * 147456;
    const unsigned short* ub   = u + ((size_t)n << 22);      // n*16384*256
    unsigned short* dtf = &dt[0][0][0][0];

    int goff[7], ldsoff[7];
#pragma unroll
    for (int k = 0; k < 7; ++k) {
        int idx = tid + (k << 8);
        goff[k] = -1; ldsoff[k] = -1;
        if (idx < 1584) {
            int r = idx / 264; int rem = idx - r * 264; int col = rem >> 2; int cg = rem & 3;
            ldsoff[k] = (cg * 396 + r * 66 + col) << 3;
            int gy = oy0 - 1 + r, gx = x0 - 1 + col;
            if ((unsigned)gy < 128u && (unsigned)gx < 128u)
                goff[k] = (((gy << 7) + gx) << 8) + (cg << 3);
        }
    }

    uint4 vreg[7];
#pragma unroll
    for (int k = 0; k < 7; ++k) {
        vreg[k] = make_uint4(0, 0, 0, 0);
        if (goff[k] >= 0) vreg[k] = *(const uint4*)(ub + goff[k]);
    }

    for (int ci = 0; ci < 8; ++ci) {
        // (a) issue THIS chunk's weight slab loads (L2-hot, short-lived regs)
        uint4 twreg[9];
        const unsigned short* wc = wsrc + ci * 18432;
#pragma unroll
        for (int j = 0; j < 9; ++j)
            twreg[j] = *(const uint4*)(wc + ((tid + (j << 8)) << 3));
        // (b) drain chunk ci data into LDS
#pragma unroll
        for (int k = 0; k < 7; ++k)
            if (ldsoff[k] >= 0) *(uint4*)(dtf + ldsoff[k]) = vreg[k];
        // (c) issue chunk ci+1 data loads
        if (ci < 7) {
            const int cn = (ci + 1) << 5;
#pragma unroll
            for (int k = 0; k < 7; ++k)
                if (goff[k] >= 0) vreg[k] = *(const uint4*)(ub + goff[k] + cn);
        }
        // (d) weights -> LDS (twreg dies here)
#pragma unroll
        for (int j = 0; j < 9; ++j)
            *(uint4*)(wl + ((tid + (j << 8)) << 3)) = twreg[j];
        __syncthreads();

        __builtin_amdgcn_s_setprio(1);
#pragma unroll
        for (int tap = 0; tap < 9; ++tap) {
            const int dy = tap / 3, dx = tap - 3 * (tap / 3);
            bf16x8 bfr[4];
#pragma unroll
            for (int g = 0; g < 4; ++g)
                bfr[g] = *(const bf16x8*)(dtf + ((q * 396 + (w + dy) * 66 + (g << 4) + m + dx) << 3));
#pragma unroll
            for (int a = 0; a < 4; ++a) {
                bf16x8 af = *(const bf16x8*)(wl + (((((tap << 2) + q) << 6) + (a << 4) + m) << 3));
#pragma unroll
                for (int g = 0; g < 4; ++g)
                    acc[a][g] = __builtin_amdgcn_mfma_f32_16x16x32_bf16(af, bfr[g], acc[a][g], 0, 0, 0);
            }
        }
        __builtin_amdgcn_s_setprio(0);
        __syncthreads();
    }

    // epilogue: out[n][oc][oy][ox] = lrelu(acc+b2) + up2(t2)*RSQRT2  (pure store)
    const int oy = oy0 + w;
    int ry0, ry1; float wy0, wy1;
    up2_coef(oy, 63, ry0, ry1, wy0, wy1);
    const unsigned short* t2b = t2 + ((size_t)n << 19);      // n*4096*128
#pragma unroll
    for (int a = 0; a < 4; ++a) {
        const int oc = oc0 + (a << 4) + (q << 2);
        float bb[4] = {b2[oc], b2[oc + 1], b2[oc + 2], b2[oc + 3]};
        float* pbase = out + ((size_t)(((n << 7) + oc) << 7) + oy) * 128;
#pragma unroll
        for (int g = 0; g < 4; ++g) {
            const int ox = x0 + (g << 4) + m;
            int cx0, cx1; float wx0, wx1;
            up2_coef(ox, 63, cx0, cx1, wx0, wx1);
            uint2 A = *(const uint2*)(t2b + (((ry0 << 6) + cx0) << 7) + oc);
            uint2 B = *(const uint2*)(t2b + (((ry0 << 6) + cx1) << 7) + oc);
            uint2 C = *(const uint2*)(t2b + (((ry1 << 6) + cx0) << 7) + oc);
            uint2 D = *(const uint2*)(t2b + (((ry1 << 6) + cx1) << 7) + oc);
            const unsigned* pA = (const unsigned*)&A; const unsigned* pB = (const unsigned*)&B;
            const unsigned* pC = (const unsigned*)&C; const unsigned* pD = (const unsigned*)&D;
#pragma unroll
            for (int r = 0; r < 4; ++r) {
                unsigned wa = pA[r >> 1], wb = pB[r >> 1], wc_ = pC[r >> 1], wd = pD[r >> 1];
                float va = (r & 1) ? bfhi(wa) : bflo(wa);
                float vb = (r & 1) ? bfhi(wb) : bflo(wb);
                float vc = (r & 1) ? bfhi(wc_) : bflo(wc_);
                float vd = (r & 1) ? bfhi(wd) : bflo(wd);
                float sk = wy0 * (wx0 * va + wx1 * vb) + wy1 * (wx0 * vc + wx1 * vd);
                pbase[(size_t)r * 16384 + ox] = lrelu_s(acc[a][g][r] + bb[r]) + sk * RSQRT2F;
            }
        }
    }
}

// ---------------------------------------------------------------------------
extern "C" void kernel_launch(void* const* d_in, const int* in_sizes, int n_in,
                              void* d_out, int out_size, void* d_ws, size_t ws_size,
                              hipStream_t stream)
{
    const float* x   = (const float*)d_in[0];
    const float* w1  = (const float*)d_in[1];
    const float* b1  = (const float*)d_in[2];
    const float* w2  = (const float*)d_in[3];
    const float* b2  = (const float*)d_in[4];
    const float* wsk = (const float*)d_in[5];
    float* out = (float*)d_out;

    unsigned short* xT  = (unsigned short*)d_ws;        // 8,388,608 elems
    unsigned short* t1  = xT + 8388608;                 // 8,388,608
    unsigned short* t2  = t1 + 8388608;                 // 4,194,304
    unsigned short* w1T = t2 + 4194304;                 // 589,824
    unsigned short* w2T = w1T + 589824;                 // 294,912
    unsigned short* wsT = w2T + 294912;                 // 32,768
    unsigned short* u   = wsT + 32768;                  // 33,554,432 (~110.9 MB total)

    k_prep  <<<dim3(5632), 256, 0, stream>>>(w1, w2, wsk, x, w1T, w2T, wsT, xT);
    k_conv1 <<<dim3(128, 4), 256, 0, stream>>>(xT, w1T, b1, t1);
    k_ss    <<<dim3(2560), 256, 0, stream>>>(xT, wsT, t1, t2, u);
    k_conv2u<<<dim3(512, 2), 256, 0, stream>>>(u, w2T, t2, b2, out);
}

// Round 9
// 253.465 us; speedup vs baseline: 1.6290x; 1.0558x over previous
//
#include <hip/hip_runtime.h>
#include <hip/hip_bf16.h>

// ResUpBlock via bf16 MFMA implicit GEMM (fp32 accumulate).
//   xT  = channels-last bf16 copy of x              [8][64][64][256]
//   t1  = lrelu(conv3x3(x,w1/48)+b1)*sqrt2 -> bf16  [8][64][64][256] (channels-last)
//   t2  = conv1x1(x, wsk/16)              -> bf16   [8][64][64][128] (channels-last)
//   u   = upsample2x(t1)                  -> bf16   [8][128][128][256]
//   out = lrelu(conv3x3(u,w2/48)+b2) + up2(t2)/sqrt2  (k_conv2u, skip fused in epilogue)
// conv1/conv2u chunk loop (round-9):
//   (1) weights: global_load_lds x9 (wave-uniform base + lane*16B linear slab ->
//       HW DMA straight to LDS; kills the reg round-trip + vmcnt-serialized wait
//       that round-5..8 paid every chunk)
//   (2) data ds_writes from vreg (run under the glds L2 latency)
//   (3) barrier (vmcnt drains only the glds; next-chunk data loads not yet issued)
//   (4) MFMA phase: FIRST issue next-chunk data loads (fly under ~1500cy of MFMA,
//       consumed at next stage's ds_write) then 9 taps of pure LDS + MFMA.
// Round-6 lesson: per-tap global weight loads re-expose L2 latency (107->194us).
// Round-4 lesson: no long-lived regs across the MFMA phase beyond vreg+acc or the
// allocator spills (WRITE_SIZE blowup). Round-8 lesson: SQ_LDS_BANK_CONFLICT const
// 6.34M across disjoint layouts -> artifact of ds-op mix, not a real stall source.
// Weight slab layout [ocb][ci][tap][q][oc64][c8]: chunk slab contiguous 36.9KB.
// mfma_f32_16x16x32_bf16: A/B frag = 8 contiguous k per lane, C/D col=lane&15,
// row=quad*4+reg (verified per guide m89/m120).

typedef __attribute__((ext_vector_type(8))) short bf16x8;
typedef __attribute__((ext_vector_type(4))) float f32x4;

#define SQRT2F  1.41421356237309504880f
#define RSQRT2F 0.70710678118654752440f

__device__ __forceinline__ float lrelu_s(float v) { return v >= 0.f ? v : 0.2f * v; }

__device__ __forceinline__ unsigned short f2bf(float f) {
    unsigned u = __builtin_bit_cast(unsigned, f);
    u += 0x7fffu + ((u >> 16) & 1u);          // RNE
    return (unsigned short)(u >> 16);
}
__device__ __forceinline__ float bflo(unsigned u) {
    return __builtin_bit_cast(float, u << 16);
}
__device__ __forceinline__ float bfhi(unsigned u) {
    return __builtin_bit_cast(float, u & 0xffff0000u);
}

// global -> LDS direct 16B copy: lds dst must be wave-uniform; lane writes dst+lane*16.
__device__ __forceinline__ void glds16(const unsigned short* g, unsigned short* l) {
    __builtin_amdgcn_global_load_lds(
        (const __attribute__((address_space(1))) void*)(const void*)g,
        (__attribute__((address_space(3))) void*)(void*)l, 16, 0, 0);
}

// bilinear 2x coefficients (align_corners=False, matches jax.image.resize; edge-clamped)
__device__ __forceinline__ void up2_coef(int o, int lim, int& i0, int& i1, float& w0, float& w1) {
    int h = o >> 1;
    if (o & 1) { i0 = h; i1 = (h + 1 > lim) ? lim : h + 1; w0 = 0.75f; w1 = 0.25f; }
    else       { i0 = (h - 1 < 0) ? 0 : h - 1; i1 = h;     w0 = 0.25f; w1 = 0.75f; }
}

// ---------------------------------------------------------------------------
// k_prep: merged weight transform (w1/w2 3x3 slab layout, wsk 1x1) + xT transpose.
// blocks [0,3584): weights; [3584,5632): xprep (64 px-tiles x 4 c-tiles x 8 n).
// ---------------------------------------------------------------------------
__global__ __launch_bounds__(256) void k_prep(const float* __restrict__ w1,
                                              const float* __restrict__ w2,
                                              const float* __restrict__ wsk,
                                              const float* __restrict__ x,
                                              unsigned short* __restrict__ w1T,
                                              unsigned short* __restrict__ w2T,
                                              unsigned short* __restrict__ wsT,
                                              unsigned short* __restrict__ xT) {
    __shared__ float t[64][65];
    const int b = blockIdx.x;
    if (b < 3584) {
        int i = b * 256 + threadIdx.x;
        if (i < 589824) {                                  // w1: 256oc x 256c x 9
            int cp  = i & 7;
            int t1i = i >> 3;  int ocp = t1i & 63;
            int t2i = t1i >> 6; int q  = t2i & 3;
            int t3  = t2i >> 2; int tap = t3 % 9;
            int t4  = t3 / 9;   int ci  = t4 & 7; int ocb = t4 >> 3;
            int oc = (ocb << 6) + ocp;
            int c  = (ci << 5) + (q << 3) + cp;
            w1T[i] = f2bf(w1[(oc * 256 + c) * 9 + tap] * (1.0f / 48.0f));
        } else if (i < 589824 + 294912) {                  // w2: 128oc x 256c x 9
            int j = i - 589824;
            int cp  = j & 7;
            int t1i = j >> 3;  int ocp = t1i & 63;
            int t2i = t1i >> 6; int q  = t2i & 3;
            int t3  = t2i >> 2; int tap = t3 % 9;
            int t4  = t3 / 9;   int ci  = t4 & 7; int ocb = t4 >> 3;
            int oc = (ocb << 6) + ocp;
            int c  = (ci << 5) + (q << 3) + cp;
            w2T[j] = f2bf(w2[(oc * 256 + c) * 9 + tap] * (1.0f / 48.0f));
        } else if (i < 589824 + 294912 + 32768) {          // wsk: 128oc x 256c
            int j = i - (589824 + 294912);
            wsT[j] = f2bf(wsk[j] * (1.0f / 16.0f));
        }
        return;
    }
    const int bb = b - 3584;
    const int p0 = (bb & 63) << 6, c0 = ((bb >> 6) & 3) << 6, n = bb >> 8;
    for (int i = threadIdx.x; i < 4096; i += 256) {
        int c = i >> 6, p = i & 63;
        t[c][p] = x[((size_t)(n * 256 + c0 + c) << 12) + p0 + p];
    }
    __syncthreads();
    for (int i = threadIdx.x; i < 4096; i += 256) {
        int p = i >> 6, c = i & 63;
        xT[((size_t)((n << 12) + p0 + p) << 8) + c0 + c] = f2bf(t[c][p]);
    }
}

// ---------------------------------------------------------------------------
// conv1: t1 = lrelu(conv3x3(x)+b1)*sqrt2. Weights glds-staged; data T14.
// block: M=64 oc x N=256 px; grid dim3(128, 4)
// ---------------------------------------------------------------------------
__global__ __launch_bounds__(256, 2) void k_conv1(
    const unsigned short* __restrict__ xT, const unsigned short* __restrict__ w1T,
    const float* __restrict__ b1, unsigned short* __restrict__ t1)
{
    __shared__ __align__(16) unsigned short dt[4][6][66][8]; // 25.3 KB, cg-planes
    __shared__ __align__(16) unsigned short wl[18432];       // 36.9 KB weight slab
    const int tid = threadIdx.x;
    const int n   = blockIdx.x >> 4;
    const int y0  = (blockIdx.x & 15) << 2;
    const int ocb = blockIdx.y;
    const int oc0 = ocb << 6;
    const int w   = tid >> 6;
    const int m   = tid & 15;
    const int q   = (tid & 63) >> 4;

    f32x4 acc[4][4];
#pragma unroll
    for (int a = 0; a < 4; ++a)
#pragma unroll
        for (int g = 0; g < 4; ++g) acc[a][g] = (f32x4){0.f, 0.f, 0.f, 0.f};

    const unsigned short* wsrc = w1T + (size_t)ocb * 147456;   // 8 chunks x 18432
    const unsigned short* xTn  = xT + ((size_t)n << 20);       // n*4096*256
    unsigned short* dtf = &dt[0][0][0][0];

    // staging slots: 1584 uint4; idx -> (r, col, cg); cg-plane LDS layout.
    int goff[7], ldsoff[7];
#pragma unroll
    for (int k = 0; k < 7; ++k) {
        int idx = tid + (k << 8);
        goff[k] = -1; ldsoff[k] = -1;
        if (idx < 1584) {
            int r = idx / 264; int rem = idx - r * 264; int col = rem >> 2; int cg = rem & 3;
            ldsoff[k] = (cg * 396 + r * 66 + col) << 3;
            int gy = y0 - 1 + r, gx = col - 1;
            if ((unsigned)gy < 64u && (unsigned)gx < 64u)
                goff[k] = (((gy << 6) + gx) << 8) + (cg << 3);
        }
    }

    // prologue: issue chunk0 data loads (OOB lanes stay zero forever)
    uint4 vreg[7];
#pragma unroll
    for (int k = 0; k < 7; ++k) {
        vreg[k] = make_uint4(0, 0, 0, 0);
        if (goff[k] >= 0) vreg[k] = *(const uint4*)(xTn + goff[k]);
    }

    for (int ci = 0; ci < 8; ++ci) {
        // (1) weights: global -> LDS direct (9 x 16B per thread, linear slab)
        const unsigned short* wc = wsrc + ci * 18432;
#pragma unroll
        for (int j = 0; j < 9; ++j)
            glds16(wc + ((tid + (j << 8)) << 3), wl + (((w << 6) + (j << 8)) << 3));
        // (2) data ds_writes (cover part of the glds latency)
#pragma unroll
        for (int k = 0; k < 7; ++k)
            if (ldsoff[k] >= 0) *(uint4*)(dtf + ldsoff[k]) = vreg[k];
        // (3) barrier: drains glds; next-chunk data loads not yet issued
        __syncthreads();

        // (4) issue chunk ci+1 data loads: fly under the whole MFMA phase
        if (ci < 7) {
            const int cn = (ci + 1) << 5;
#pragma unroll
            for (int k = 0; k < 7; ++k)
                if (goff[k] >= 0) vreg[k] = *(const uint4*)(xTn + goff[k] + cn);
        }

        __builtin_amdgcn_s_setprio(1);
#pragma unroll
        for (int tap = 0; tap < 9; ++tap) {
            const int dy = tap / 3, dx = tap - 3 * (tap / 3);
            bf16x8 bfr[4];
#pragma unroll
            for (int g = 0; g < 4; ++g)
                bfr[g] = *(const bf16x8*)(dtf + ((q * 396 + (w + dy) * 66 + (g << 4) + m + dx) << 3));
#pragma unroll
            for (int a = 0; a < 4; ++a) {
                bf16x8 af = *(const bf16x8*)(wl + (((((tap << 2) + q) << 6) + (a << 4) + m) << 3));
#pragma unroll
                for (int g = 0; g < 4; ++g)
                    acc[a][g] = __builtin_amdgcn_mfma_f32_16x16x32_bf16(af, bfr[g], acc[a][g], 0, 0, 0);
            }
        }
        __builtin_amdgcn_s_setprio(0);
        __syncthreads();
    }

    // epilogue: lane holds 4 consecutive oc (q*4+r) at px (g*16+m) -> 8B bf16 stores
    const int y = y0 + w;
#pragma unroll
    for (int a = 0; a < 4; ++a) {
        const int oc = oc0 + (a << 4) + (q << 2);
        float b0 = b1[oc], b1v = b1[oc + 1], b2v = b1[oc + 2], b3 = b1[oc + 3];
#pragma unroll
        for (int g = 0; g < 4; ++g) {
            const int xcol = (g << 4) + m;
            unsigned lo = (unsigned)f2bf(lrelu_s(acc[a][g][0] + b0) * SQRT2F)
                        | ((unsigned)f2bf(lrelu_s(acc[a][g][1] + b1v) * SQRT2F) << 16);
            unsigned hi = (unsigned)f2bf(lrelu_s(acc[a][g][2] + b2v) * SQRT2F)
                        | ((unsigned)f2bf(lrelu_s(acc[a][g][3] + b3) * SQRT2F) << 16);
            uint2 s; s.x = lo; s.y = hi;
            *(uint2*)(t1 + (((n << 12) + (y << 6) + xcol) << 8) + oc) = s;
        }
    }
}

// ---------------------------------------------------------------------------
// k_ss: merged skip GEMM + synthu.
// blocks [0,512): skip (64 px x 128 oc GEMM); [512,2560): synthu bilinear.
// ---------------------------------------------------------------------------
__global__ __launch_bounds__(256, 2) void k_ss(
    const unsigned short* __restrict__ xT, const unsigned short* __restrict__ wsT,
    const unsigned short* __restrict__ t1, unsigned short* __restrict__ t2,
    unsigned short* __restrict__ u)
{
    const int b = blockIdx.x;
    const int tid = threadIdx.x;
    if (b < 512) {
        const int w = tid >> 6, m = tid & 15, q = (tid & 63) >> 4;
        const int px0 = b << 6;
        const int apx = px0 + (w << 4) + m;

        f32x4 acc[8];
#pragma unroll
        for (int g = 0; g < 8; ++g) acc[g] = (f32x4){0.f, 0.f, 0.f, 0.f};

#pragma unroll
        for (int c0 = 0; c0 < 256; c0 += 32) {
            bf16x8 af = *(const bf16x8*)(xT + ((size_t)apx << 8) + c0 + (q << 3));
#pragma unroll
            for (int g = 0; g < 8; ++g) {
                bf16x8 bf = *(const bf16x8*)(wsT + (((g << 4) + m) << 8) + c0 + (q << 3));
                acc[g] = __builtin_amdgcn_mfma_f32_16x16x32_bf16(af, bf, acc[g], 0, 0, 0);
            }
        }
#pragma unroll
        for (int g = 0; g < 8; ++g) {
            const int oc = (g << 4) + m;
#pragma unroll
            for (int r = 0; r < 4; ++r) {
                int opx = px0 + (w << 4) + (q << 2) + r;
                t2[((size_t)opx << 7) + oc] = f2bf(acc[g][r]);
            }
        }
        return;
    }
    // synthu: u[n][oy][ox][c] = bilinear2x(t1)
    const int bb = b - 512;
    const int n = bb >> 8, oy = (bb >> 1) & 127, x0 = (bb & 1) << 6;
    int ry0, ry1; float wy0, wy1;
    up2_coef(oy, 63, ry0, ry1, wy0, wy1);
    const unsigned short* tb = t1 + ((size_t)n << 20);           // n*4096*256
    unsigned short* ub = u + ((size_t)((n << 7) + oy) << 15);    // row = 128*256 elems

    for (int idx = tid; idx < 2048; idx += 256) {
        const int ox = x0 + (idx >> 5), g = idx & 31;
        int cx0, cx1; float wx0, wx1;
        up2_coef(ox, 63, cx0, cx1, wx0, wx1);
        const int co = g << 3;
        uint4 v00 = *(const uint4*)(tb + (((ry0 << 6) + cx0) << 8) + co);
        uint4 v01 = *(const uint4*)(tb + (((ry0 << 6) + cx1) << 8) + co);
        uint4 v10 = *(const uint4*)(tb + (((ry1 << 6) + cx0) << 8) + co);
        uint4 v11 = *(const uint4*)(tb + (((ry1 << 6) + cx1) << 8) + co);
        const unsigned* pa = (const unsigned*)&v00; const unsigned* pb = (const unsigned*)&v01;
        const unsigned* pc = (const unsigned*)&v10; const unsigned* pd = (const unsigned*)&v11;
        uint4 res; unsigned* pr = (unsigned*)&res;
#pragma unroll
        for (int j = 0; j < 4; ++j) {
            float vlo = wy0 * (wx0 * bflo(pa[j]) + wx1 * bflo(pb[j]))
                      + wy1 * (wx0 * bflo(pc[j]) + wx1 * bflo(pd[j]));
            float vhi = wy0 * (wx0 * bfhi(pa[j]) + wx1 * bfhi(pb[j]))
                      + wy1 * (wx0 * bfhi(pc[j]) + wx1 * bfhi(pd[j]));
            pr[j] = (unsigned)f2bf(vlo) | ((unsigned)f2bf(vhi) << 16);
        }
        *(uint4*)(ub + (ox << 8) + co) = res;
    }
}

// ---------------------------------------------------------------------------
// k_conv2u: out = lrelu(conv3x3(u)+b2) + up2(t2)*RSQRT2. Weights glds-staged;
// data T14. block: M=64 oc x N=256 px; grid dim3(512, 2)
// ---------------------------------------------------------------------------
__global__ __launch_bounds__(256, 2) void k_conv2u(
    const unsigned short* __restrict__ u, const unsigned short* __restrict__ w2T,
    const unsigned short* __restrict__ t2, const float* __restrict__ b2,
    float* __restrict__ out)
{
    __shared__ __align__(16) unsigned short dt[4][6][66][8]; // 25.3 KB, cg-planes
    __shared__ __align__(16) unsigned short wl[18432];       // 36.9 KB
    const int tid  = threadIdx.x;
    const int n    = blockIdx.x >> 6;
    const int rest = blockIdx.x & 63;
    const int oy0  = (rest >> 1) << 2;
    const int x0   = (rest & 1) << 6;
    const int ocb  = blockIdx.y;
    const int oc0  = ocb << 6;
    const int w    = tid >> 6;
    const int m    = tid & 15;
    const int q    = (tid & 63) >> 4;

    f32x4 acc[4][4];
#pragma unroll
    for (int a = 0; a < 4; ++a)
#pragma unroll
        for (int g = 0; g < 4; ++g) acc[a][g] = (f32x4){0.f, 0.f, 0.f, 0.f};

    const unsigned short* wsrc = w2T + (size_t)ocb * 147456;
    const unsigned short* ub   = u + ((size_t)n << 22);      // n*16384*256
    unsigned short* dtf = &dt[0][0][0][0];

    int goff[7], ldsoff[7];
#pragma unroll
    for (int k = 0; k < 7; ++k) {
        int idx = tid + (k << 8);
        goff[k] = -1; ldsoff[k] = -1;
        if (idx < 1584) {
            int r = idx / 264; int rem = idx - r * 264; int col = rem >> 2; int cg = rem & 3;
            ldsoff[k] = (cg * 396 + r * 66 + col) << 3;
            int gy = oy0 - 1 + r, gx = x0 - 1 + col;
            if ((unsigned)gy < 128u && (unsigned)gx < 128u)
                goff[k] = (((gy << 7) + gx) << 8) + (cg << 3);
        }
    }

    uint4 vreg[7];
#pragma unroll
    for (int k = 0; k < 7; ++k) {
        vreg[k] = make_uint4(0, 0, 0, 0);
        if (goff[k] >= 0) vreg[k] = *(const uint4*)(ub + goff[k]);
    }

    for (int ci = 0; ci < 8; ++ci) {
        // (1) weights: global -> LDS direct
        const unsigned short* wc = wsrc + ci * 18432;
#pragma unroll
        for (int j = 0; j < 9; ++j)
            glds16(wc + ((tid + (j << 8)) << 3), wl + (((w << 6) + (j << 8)) << 3));
        // (2) data ds_writes
#pragma unroll
        for (int k = 0; k < 7; ++k)
            if (ldsoff[k] >= 0) *(uint4*)(dtf + ldsoff[k]) = vreg[k];
        // (3) barrier
        __syncthreads();

        // (4) issue chunk ci+1 data loads under the MFMA phase
        if (ci < 7) {
            const int cn = (ci + 1) << 5;
#pragma unroll
            for (int k = 0; k < 7; ++k)
                if (goff[k] >= 0) vreg[k] = *(const uint4*)(ub + goff[k] + cn);
        }

        __builtin_amdgcn_s_setprio(1);
#pragma unroll
        for (int tap = 0; tap < 9; ++tap) {
            const int dy = tap / 3, dx = tap - 3 * (tap / 3);
            bf16x8 bfr[4];
#pragma unroll
            for (int g = 0; g < 4; ++g)
                bfr[g] = *(const bf16x8*)(dtf + ((q * 396 + (w + dy) * 66 + (g << 4) + m + dx) << 3));
#pragma unroll
            for (int a = 0; a < 4; ++a) {
                bf16x8 af = *(const bf16x8*)(wl + (((((tap << 2) + q) << 6) + (a << 4) + m) << 3));
#pragma unroll
                for (int g = 0; g < 4; ++g)
                    acc[a][g] = __builtin_amdgcn_mfma_f32_16x16x32_bf16(af, bfr[g], acc[a][g], 0, 0, 0);
            }
        }
        __builtin_amdgcn_s_setprio(0);
        __syncthreads();
    }

    // epilogue: out[n][oc][oy][ox] = lrelu(acc+b2) + up2(t2)*RSQRT2  (pure store)
    const int oy = oy0 + w;
    int ry0, ry1; float wy0, wy1;
    up2_coef(oy, 63, ry0, ry1, wy0, wy1);
    const unsigned short* t2b = t2 + ((size_t)n << 19);      // n*4096*128
#pragma unroll
    for (int a = 0; a < 4; ++a) {
        const int oc = oc0 + (a << 4) + (q << 2);
        float bb[4] = {b2[oc], b2[oc + 1], b2[oc + 2], b2[oc + 3]};
        float* pbase = out + ((size_t)(((n << 7) + oc) << 7) + oy) * 128;
#pragma unroll
        for (int g = 0; g < 4; ++g) {
            const int ox = x0 + (g << 4) + m;
            int cx0, cx1; float wx0, wx1;
            up2_coef(ox, 63, cx0, cx1, wx0, wx1);
            uint2 A = *(const uint2*)(t2b + (((ry0 << 6) + cx0) << 7) + oc);
            uint2 B = *(const uint2*)(t2b + (((ry0 << 6) + cx1) << 7) + oc);
            uint2 C = *(const uint2*)(t2b + (((ry1 << 6) + cx0) << 7) + oc);
            uint2 D = *(const uint2*)(t2b + (((ry1 << 6) + cx1) << 7) + oc);
            const unsigned* pA = (const unsigned*)&A; const unsigned* pB = (const unsigned*)&B;
            const unsigned* pC = (const unsigned*)&C; const unsigned* pD = (const unsigned*)&D;
#pragma unroll
            for (int r = 0; r < 4; ++r) {
                unsigned wa = pA[r >> 1], wb = pB[r >> 1], wc_ = pC[r >> 1], wd = pD[r >> 1];
                float va = (r & 1) ? bfhi(wa) : bflo(wa);
                float vb = (r & 1) ? bfhi(wb) : bflo(wb);
                float vc = (r & 1) ? bfhi(wc_) : bflo(wc_);
                float vd = (r & 1) ? bfhi(wd) : bflo(wd);
                float sk = wy0 * (wx0 * va + wx1 * vb) + wy1 * (wx0 * vc + wx1 * vd);
                pbase[(size_t)r * 16384 + ox] = lrelu_s(acc[a][g][r] + bb[r]) + sk * RSQRT2F;
            }
        }
    }
}

// ---------------------------------------------------------------------------
extern "C" void kernel_launch(void* const* d_in, const int* in_sizes, int n_in,
                              void* d_out, int out_size, void* d_ws, size_t ws_size,
                              hipStream_t stream)
{
    const float* x   = (const float*)d_in[0];
    const float* w1  = (const float*)d_in[1];
    const float* b1  = (const float*)d_in[2];
    const float* w2  = (const float*)d_in[3];
    const float* b2  = (const float*)d_in[4];
    const float* wsk = (const float*)d_in[5];
    float* out = (float*)d_out;

    unsigned short* xT  = (unsigned short*)d_ws;        // 8,388,608 elems
    unsigned short* t1  = xT + 8388608;                 // 8,388,608
    unsigned short* t2  = t1 + 8388608;                 // 4,194,304
    unsigned short* w1T = t2 + 4194304;                 // 589,824
    unsigned short* w2T = w1T + 589824;                 // 294,912
    unsigned short* wsT = w2T + 294912;                 // 32,768
    unsigned short* u   = wsT + 32768;                  // 33,554,432 (~110.9 MB total)

    k_prep  <<<dim3(5632), 256, 0, stream>>>(w1, w2, wsk, x, w1T, w2T, wsT, xT);
    k_conv1 <<<dim3(128, 4), 256, 0, stream>>>(xT, w1T, b1, t1);
    k_ss    <<<dim3(2560), 256, 0, stream>>>(xT, wsT, t1, t2, u);
    k_conv2u<<<dim3(512, 2), 256, 0, stream>>>(u, w2T, t2, b2, out);
}